// Round 11
// baseline (90.391 us; speedup 1.0000x reference)
//
#include <hip/hip_runtime.h>
#include <math.h>

using short8  = __attribute__((ext_vector_type(8))) short;
using ushort8 = __attribute__((ext_vector_type(8))) unsigned short;
using f32x4   = __attribute__((ext_vector_type(4))) float;

constexpr int DIM = 1024, NB = 8, NH = 2, HD = 32;
constexpr float SCALE = 0.17677669529663687f;  // HD^-0.5, folded into wq at prep
constexpr int SXW = 1032;   // x-tile row stride (ushorts)
constexpr int SQW = 1544;   // qkv row stride (ushorts)

__device__ __forceinline__ unsigned short f2bf(float f) {
  unsigned u = __float_as_uint(f);
  u += 0x7fff + ((u >> 16) & 1);  // RNE
  return (unsigned short)(u >> 16);
}
__device__ __forceinline__ float bf2f(unsigned short h) {
  return __uint_as_float((unsigned)h << 16);
}
__device__ __forceinline__ unsigned pack2bf(float lo, float hi) {
  return (unsigned)f2bf(lo) | ((unsigned)f2bf(hi) << 16);
}

// q/k region addressing with bank swizzle: logical (n, h, dd) ->
// R = 2n+h (32-ushort row), 8-ushort block (dd>>3) XOR'd by (R&3).
__device__ __forceinline__ int qk_off(int R, int blk, int sub) {
  return R * 32 + ((blk ^ (R & 3)) * 8) + sub;
}

// ---- prep: weights -> bf16 in MFMA fragment order (verified round 5/7) ----
__global__ __launch_bounds__(256) void prep_weights(
    const float* __restrict__ wq, const float* __restrict__ wk,
    const float* __restrict__ wv, const float* __restrict__ wf,
    unsigned short* __restrict__ ws)
{
  int gid = blockIdx.x * 256 + threadIdx.x;   // 0..262143
  if (gid < 196608) {
    int t = gid >> 11, r = gid & 2047;
    int s = r >> 9, l = (r >> 3) & 63, z = r & 7;
    int met = t >> 3, n = t & 7, m = met >> 2, et = met & 3;
    int fr = l & 15, fg = l >> 4;
    int e = et * 16 + fr, k = s * 32 + fg * 8 + z;
    const float* w = (m == 0) ? wq : (m == 1) ? wk : wv;
    float v = w[n * 8192 + k * 64 + e];
    if (m == 0) v *= SCALE;
    ws[gid] = f2bf(v);
  } else {
    int g2 = gid - 196608;
    int t = g2 >> 10, r = g2 & 1023;
    int s = r >> 9, l = (r >> 3) & 63, z = r & 7;
    int n = t >> 3, et = t & 7;
    int fr = l & 15, fg = l >> 4;
    int eo = et * 16 + fr, k = s * 32 + fg * 8 + z;
    ws[gid] = f2bf(wf[n * 8192 + k * 128 + eo]);
  }
}

// ---- fused kernel: 16 tokens/WG, 512 threads, attention fully on MFMA ----
__global__ __launch_bounds__(512, 4) void gc_fused(
    const float* __restrict__ x,
    const unsigned short* __restrict__ wsw,   // 96 qkv tiles [2048]
    const unsigned short* __restrict__ wsf,   // 64 wf tiles  [1024]
    float* __restrict__ out)
{
  // overlays: stage-x rows at r*SXW; after barrier qkv rows at t*SQW.
  // per token row: q/attn_out [0,512) swizzled qk_off | k [512,1024) swizzled |
  // vT planes [1024,1536): 1024 + kh*256 + dd*8 + (k&7).
  __shared__ __align__(16) unsigned short smem[16 * SQW];   // 49408 B

  const int tid  = threadIdx.x;
  const int lane = tid & 63;
  const int w    = tid >> 6;
  const int fr   = lane & 15;
  const int fg   = lane >> 4;
  const long tok0 = (long)blockIdx.x * 16;

  // ---- stage x -> bf16 LDS (coalesced; proven) ----
  {
    const float* xb = x + tok0 * DIM;
    float4 xa[4], xc[4];
    #pragma unroll
    for (int jj = 0; jj < 4; ++jj) {
      int chunk = tid + 512 * jj;                  // 32B chunks, 128 per token row
      const float* src = xb + (long)(chunk >> 7) * DIM + (chunk & 127) * 8;
      xa[jj] = *reinterpret_cast<const float4*>(src);
      xc[jj] = *reinterpret_cast<const float4*>(src + 4);
    }
    #pragma unroll
    for (int jj = 0; jj < 4; ++jj) {
      int chunk = tid + 512 * jj;
      ushort8 v;
      v[0] = f2bf(xa[jj].x); v[1] = f2bf(xa[jj].y);
      v[2] = f2bf(xa[jj].z); v[3] = f2bf(xa[jj].w);
      v[4] = f2bf(xc[jj].x); v[5] = f2bf(xc[jj].y);
      v[6] = f2bf(xc[jj].z); v[7] = f2bf(xc[jj].w);
      *reinterpret_cast<ushort8*>(&smem[(chunk >> 7) * SXW + (chunk & 127) * 8]) = v;
    }
  }
  __syncthreads();

  // ---- phase A: 96 QKV tiles over 8 waves; 4-deep weight-load ring ----
  ushort4 qreg[12];
  {
    short8 wfrag[4][4];                            // 64 VGPR ring, 4 tiles in flight
    #pragma unroll
    for (int p = 0; p < 4; ++p) {
      const unsigned short* wp = wsw + (w * 12 + p) * 2048 + lane * 8;
      #pragma unroll
      for (int s = 0; s < 4; ++s)
        wfrag[p][s] = *reinterpret_cast<const short8*>(wp + s * 512);
    }
    #pragma unroll
    for (int j = 0; j < 12; ++j) {
      const int n = (w * 12 + j) & 7;
      short8 bfr[4];
      #pragma unroll
      for (int s = 0; s < 4; ++s)
        bfr[s] = *reinterpret_cast<const short8*>(&smem[fr * SXW + n * 128 + s * 32 + fg * 8]);
      f32x4 acc = {0.f, 0.f, 0.f, 0.f};
      #pragma unroll
      for (int s = 0; s < 4; ++s)
        acc = __builtin_amdgcn_mfma_f32_16x16x32_bf16(wfrag[j & 3][s], bfr[s], acc, 0, 0, 0);
      if (j + 4 < 12) {                            // refill consumed slot (WAR ok)
        const unsigned short* wp = wsw + (w * 12 + j + 4) * 2048 + lane * 8;
        #pragma unroll
        for (int s = 0; s < 4; ++s)
          wfrag[j & 3][s] = *reinterpret_cast<const short8*>(wp + s * 512);
      }
      ushort4 d4;
      d4.x = f2bf(acc[0]); d4.y = f2bf(acc[1]);
      d4.z = f2bf(acc[2]); d4.w = f2bf(acc[3]);
      qreg[j] = d4;
    }
  }
  __syncthreads();                                 // x region dies

  // ---- write qkv frags: q/k swizzled, vT as two k-half planes ----
  {
    #pragma unroll
    for (int j = 0; j < 12; ++j) {
      const int cc = w * 12 + j;
      const int met = cc >> 3, n = cc & 7;
      const int m = met >> 2, e0 = (met & 3) * 16;
      if (m < 2) {
        const int e00 = e0 + fg * 4;               // 4-aligned, block-constant over r
        const int h = e00 >> 5, dd0 = e00 & 31;
        const int R = 2 * n + h;
        *reinterpret_cast<ushort4*>(
            &smem[fr * SQW + m * 512 + qk_off(R, dd0 >> 3, dd0 & 7)]) = qreg[j];
      } else {
        const unsigned short vals[4] = {qreg[j].x, qreg[j].y, qreg[j].z, qreg[j].w};
        #pragma unroll
        for (int r = 0; r < 4; ++r) {
          const int e = e0 + fg * 4 + r, dd = e & 31, h = e >> 5;
          smem[fr * SQW + 1024 + h * 256 + dd * 8 + n] = vals[r];  // plane kh=h, k&7=n
        }
      }
    }
  }
  __syncthreads();

  // ---- phase B': scores (MFMA) + softmax + PV (MFMA chain); proven round 9 ----
  {
    const int la = lane & 15, ga = lane >> 4;
    const int R  = 2 * (la & 7) + (la >> 3);       // (n, h) row of this lane's col
    const int qoff = qk_off(R, ga, 0);
    const bool useful = ((ga >> 1) == (la >> 3));
    const bool kvalid = (ga < 2);
    const int srcA = (ga * 32 + la) & 63;
    #pragma unroll
    for (int tt = 0; tt < 2; ++tt) {
      const int t = w * 2 + tt;
      const unsigned short* tb = &smem[t * SQW];
      short8 kfr = *reinterpret_cast<const short8*>(tb + 512 + qoff);
      short8 qfr = *reinterpret_cast<const short8*>(tb + qoff);
      f32x4 zero = {0.f, 0.f, 0.f, 0.f};
      f32x4 s = __builtin_amdgcn_mfma_f32_16x16x32_bf16(kfr, qfr, zero, 0, 0, 0);
      float m4 = fmaxf(fmaxf(s[0], s[1]), fmaxf(s[2], s[3]));
      float mx = fmaxf(m4, __shfl_xor(m4, 16));
      float e0 = __expf(s[0] - mx), e1 = __expf(s[1] - mx);
      float e2 = __expf(s[2] - mx), e3 = __expf(s[3] - mx);
      float sm  = e0 + e1 + e2 + e3;
      float smt = sm + __shfl_xor(sm, 16);
      float inv = useful ? (1.f / smt) : 0.f;      // smt >= 1 for useful lanes
      unsigned pk01 = pack2bf(e0 * inv, e1 * inv);
      unsigned pk23 = pack2bf(e2 * inv, e3 * inv);
      unsigned b0 = (unsigned)__builtin_amdgcn_ds_bpermute(srcA * 4, (int)pk01);
      unsigned b1 = (unsigned)__builtin_amdgcn_ds_bpermute(srcA * 4, (int)pk23);
      unsigned b2 = (unsigned)__builtin_amdgcn_ds_bpermute(((srcA + 16) & 63) * 4, (int)pk01);
      unsigned b3 = (unsigned)__builtin_amdgcn_ds_bpermute(((srcA + 16) & 63) * 4, (int)pk23);
      union { unsigned u[4]; short8 s8; } pb;
      pb.u[0] = kvalid ? b0 : 0u;  pb.u[1] = kvalid ? b1 : 0u;
      pb.u[2] = kvalid ? b2 : 0u;  pb.u[3] = kvalid ? b3 : 0u;
      #pragma unroll
      for (int dh = 0; dh < 2; ++dh) {
        // A[row=dd=dh*16+la][k=ga*8+j] from vT plane (ga&1); rows>=16 of B are 0.
        short8 va = *reinterpret_cast<const short8*>(
            tb + 1024 + (ga & 1) * 256 + (dh * 16 + la) * 8);
        f32x4 o = __builtin_amdgcn_mfma_f32_16x16x32_bf16(va, pb.s8, zero, 0, 0, 0);
        ushort4 ou;
        ou.x = f2bf(o[0]); ou.y = f2bf(o[1]); ou.z = f2bf(o[2]); ou.w = f2bf(o[3]);
        const int blk = 2 * dh + (ga >> 1);        // dd block of this quarter
        *reinterpret_cast<ushort4*>(
            &smem[t * SQW + qk_off(R, blk, (ga & 1) * 4)]) = ou;
      }
    }
  }
  __syncthreads();

  // ---- phase D: out = attn_out @ wf; wave w owns n = w; batched wf loads ----
  {
    const int n = w;
    short8 wfd[8][2];                              // all 16 L2 loads in flight
    #pragma unroll
    for (int et = 0; et < 8; ++et) {
      const unsigned short* wp = wsf + (n * 8 + et) * 1024 + lane * 8;
      wfd[et][0] = *reinterpret_cast<const short8*>(wp);
      wfd[et][1] = *reinterpret_cast<const short8*>(wp + 512);
    }
    short8 bfr[2];
    #pragma unroll
    for (int s = 0; s < 2; ++s) {
      const int R = 2 * n + s;                     // h = s, dd = fg*8 -> blk = fg
      bfr[s] = *reinterpret_cast<const short8*>(&smem[fr * SQW + qk_off(R, fg, 0)]);
    }
    #pragma unroll
    for (int et = 0; et < 8; ++et) {
      f32x4 acc = {0.f, 0.f, 0.f, 0.f};
      #pragma unroll
      for (int s = 0; s < 2; ++s)
        acc = __builtin_amdgcn_mfma_f32_16x16x32_bf16(wfd[et][s], bfr[s], acc, 0, 0, 0);
      float4 o; o.x = acc[0]; o.y = acc[1]; o.z = acc[2]; o.w = acc[3];
      *reinterpret_cast<float4*>(out + (tok0 + fr) * DIM + n * 128 + et * 16 + fg * 4) = o;
    }
  }
}

extern "C" void kernel_launch(void* const* d_in, const int* in_sizes, int n_in,
                              void* d_out, int out_size, void* d_ws, size_t ws_size,
                              hipStream_t stream) {
  const float* x  = (const float*)d_in[0];
  const float* wq = (const float*)d_in[1];
  const float* wk = (const float*)d_in[2];
  const float* wv = (const float*)d_in[3];
  const float* wf = (const float*)d_in[4];
  float* out = (float*)d_out;
  unsigned short* ws = (unsigned short*)d_ws;

  prep_weights<<<dim3(1024), dim3(256), 0, stream>>>(wq, wk, wv, wf, ws);

  const int tokens = in_sizes[0] / DIM;   // 32768
  gc_fused<<<dim3(tokens / 16), dim3(512), 0, stream>>>(x, ws, ws + 196608, out);
}